// Round 3
// baseline (443.591 us; speedup 1.0000x reference)
//
#include <hip/hip_runtime.h>

// Sparsity_Checker: fused passthrough-copy + collector histogram + finalize.
// All four reference outputs derive from the 5-bin histogram of
// collector = sum_t spikes[t] (values 0..T):
//   unique_counts[k]  = hist[k]
//   coll_zero_frac    = hist[0] / total
//   sparsity_ratio    = (total*T - sum_k k*hist[k]) / (total*T)
// Memory-bound: 205.5 MB read + 205.5 MB write ≈ 65 µs floor at 6.3 TB/s.
// Finalize is fused via a last-block-done ticket (saves one launch).

constexpr int T_STEPS = 4;

// clang ext-vector type: __builtin_nontemporal_* rejects HIP_vector_type
// (a class), but accepts native vector types. Same 16-B layout as float4.
typedef float vfloat4 __attribute__((ext_vector_type(4)));

__global__ __launch_bounds__(256) void spike_stats_kernel(
    const vfloat4* __restrict__ in, vfloat4* __restrict__ out,
    unsigned int* __restrict__ hist,  // hist[0..4] bins, hist[5] done-ticket
    float* __restrict__ tail, int nvec, double total)
{
    __shared__ unsigned int lhist[5];
    __shared__ unsigned int s_prev;
    if (threadIdx.x < 5) lhist[threadIdx.x] = 0u;
    __syncthreads();

    // packed histogram: 5 bins x 12 bits. grid=2048x256 -> <=7 iters/thread,
    // per-wave bin max = 64 lanes * 4 elems * 7 iters = 1792 < 4096. No overflow.
    unsigned long long packed = 0ull;

    const int stride = gridDim.x * blockDim.x;
    for (int v = blockIdx.x * blockDim.x + threadIdx.x; v < nvec; v += stride) {
        vfloat4 a0 = __builtin_nontemporal_load(&in[0 * nvec + v]);
        vfloat4 a1 = __builtin_nontemporal_load(&in[1 * nvec + v]);
        vfloat4 a2 = __builtin_nontemporal_load(&in[2 * nvec + v]);
        vfloat4 a3 = __builtin_nontemporal_load(&in[3 * nvec + v]);
        __builtin_nontemporal_store(a0, &out[0 * nvec + v]);
        __builtin_nontemporal_store(a1, &out[1 * nvec + v]);
        __builtin_nontemporal_store(a2, &out[2 * nvec + v]);
        __builtin_nontemporal_store(a3, &out[3 * nvec + v]);
        // elements are exactly 0.0f or 1.0f -> sums are exact small ints
        vfloat4 s = a0 + a1 + a2 + a3;
        packed += (1ull << ((int)s.x * 12)) + (1ull << ((int)s.y * 12))
                + (1ull << ((int)s.z * 12)) + (1ull << ((int)s.w * 12));
    }

    // wave-64 butterfly reduce of the packed histogram
#pragma unroll
    for (int off = 32; off > 0; off >>= 1)
        packed += __shfl_down(packed, off, 64);

    if ((threadIdx.x & 63) == 0) {
#pragma unroll
        for (int k = 0; k < 5; ++k)
            atomicAdd(&lhist[k], (unsigned int)((packed >> (12 * k)) & 0xFFFull));
    }
    __syncthreads();

    // 5 device-scope atomics per block (2048 blocks, 5 addresses) — negligible
    if (threadIdx.x < 5)
        atomicAdd(&hist[threadIdx.x], lhist[threadIdx.x]);
    __syncthreads();  // all 5 hist atomics of this block retired (waitcnt+barrier)

    // last-block-done ticket: the final arriver computes the stats tail
    if (threadIdx.x == 0) {
        __threadfence();                       // order hist adds before ticket
        s_prev = atomicAdd(&hist[5], 1u);
    }
    __syncthreads();
    if (threadIdx.x == 0 && s_prev == gridDim.x - 1) {
        unsigned int h[5];
#pragma unroll
        for (int k = 0; k < 5; ++k)
            h[k] = atomicAdd(&hist[k], 0u);    // coherent device-scope read
        double spikes_sum = 0.0;
#pragma unroll
        for (int k = 0; k < 5; ++k)
            spikes_sum += (double)k * (double)h[k];
        double denom = total * (double)T_STEPS;
        tail[0] = (float)((denom - spikes_sum) / denom); // sparsity_ratio
        tail[1] = (float)((double)h[0] / total);         // coll_zero_frac
#pragma unroll
        for (int k = 0; k < 5; ++k)
            tail[2 + k] = (float)h[k];         // unique_counts (exact: < 2^24)
    }
}

extern "C" void kernel_launch(void* const* d_in, const int* in_sizes, int n_in,
                              void* d_out, int out_size, void* d_ws, size_t ws_size,
                              hipStream_t stream)
{
    const float* spikes = (const float*)d_in[0];
    float* out = (float*)d_out;

    const long n = (long)in_sizes[0];       // T*B*C*H*W = 51,380,224
    const long per_t = n / T_STEPS;         // 12,845,056 elements per timestep
    const int nvec = (int)(per_t / 4);      // 3,211,264 float4 per timestep

    unsigned int* hist = (unsigned int*)d_ws;  // 5 bins + 1 ticket
    (void)hipMemsetAsync(d_ws, 0, 6 * sizeof(unsigned int), stream);

    // grid=2048 (8 blocks/CU): max memory-level parallelism, short tail,
    // packed-histogram overflow bound still safe (see kernel comment).
    spike_stats_kernel<<<dim3(2048), dim3(256), 0, stream>>>(
        (const vfloat4*)spikes, (vfloat4*)out, hist, out + n, nvec, (double)per_t);
}